// Round 5
// baseline (566.834 us; speedup 1.0000x reference)
//
#include <hip/hip_runtime.h>

#define NB 16

typedef unsigned short ushort_t;
typedef unsigned int uint32;
using short8  = __attribute__((ext_vector_type(8))) short;
using floatx4 = __attribute__((ext_vector_type(4))) float;

__device__ __forceinline__ float silu_f(float x){ return x * (1.0f/(1.0f+__expf(-x))); }
__device__ __forceinline__ float sigm_f(float x){ return 1.0f/(1.0f+__expf(-x)); }
__device__ __forceinline__ ushort_t f2bf(float f){
  uint32 u = __float_as_uint(f);
  u += 0x7fffu + ((u>>16)&1u);          // RNE
  return (ushort_t)(u>>16);
}
__device__ __forceinline__ float bf2f(ushort_t h){ return __uint_as_float(((uint32)h)<<16); }
// round-half-up bf16 pair pack: 3 VALU ops per 2 elements
__device__ __forceinline__ uint32 pack_rhu(float f0, float f1){
  uint32 u0 = __float_as_uint(f0) + 0x8000u;
  uint32 u1 = __float_as_uint(f1) + 0x8000u;
  return __builtin_amdgcn_perm(u1, u0, 0x07060302u);  // {u1.hi16, u0.hi16}
}

// ---------------------------------------------------------------------------
// Weight conversion to one bf16 blob. ushort offsets:
//   0        stemW0 12288
//   12288    stemW1 24576
//   36864    stemW2 49152
//   86016    cls_w1 55296
//   141312   reg_w1 55296
//   196608   cls_w2 55296
//   251904   reg_w2 55296
//   307200   clsp_w 23040
//   330240   cls_wdT 5184   ([lvl][j][c] transposed)
//   335424   reg_wdT 5184
//   340608   total
// ---------------------------------------------------------------------------
__global__ __launch_bounds__(256) void wconv_k(
    const float* __restrict__ s0, const float* __restrict__ s1,
    const float* __restrict__ s2, const float* __restrict__ cw1,
    const float* __restrict__ rw1, const float* __restrict__ cw2,
    const float* __restrict__ rw2, const float* __restrict__ chw,
    const float* __restrict__ cwd, const float* __restrict__ rwd,
    ushort_t* __restrict__ dst)
{
  int i = blockIdx.x*256 + threadIdx.x;
  if (i >= 340608) return;
  if (i < 330240) {
    const float* p; int off;
    if      (i < 12288)  { p = s0;  off = i; }
    else if (i < 36864)  { p = s1;  off = i - 12288; }
    else if (i < 86016)  { p = s2;  off = i - 36864; }
    else if (i < 141312) { p = cw1; off = i - 86016; }
    else if (i < 196608) { p = rw1; off = i - 141312; }
    else if (i < 251904) { p = cw2; off = i - 196608; }
    else if (i < 307200) { p = rw2; off = i - 251904; }
    else                 { p = chw; off = i - 307200; }
    dst[i] = f2bf(p[off]);
  } else {
    int rel = i - 330240;
    int br = rel / 5184; int r2 = rel - br*5184;
    int lvl = r2 / 1728; int r3 = r2 - lvl*1728;
    int j = r3 / 192;    int c = r3 - j*192;
    const float* wd = br ? rwd : cwd;
    dst[i] = f2bf(wd[lvl*1728 + c*9 + j]);
  }
}

// ---------------------------------------------------------------------------
// Stem GEMM directly from NCHW fp32. A = weights [co][ci] (6 M-tiles of 16),
// B = x NCHW (positions). Block = 128 pos (4 waves x 32 pos), grid 1050.
// ---------------------------------------------------------------------------
__global__ __launch_bounds__(256) void stem_k(
    const float* __restrict__ x0, const float* __restrict__ x1,
    const float* __restrict__ x2, const ushort_t* __restrict__ Wb,
    const float* __restrict__ sb0, const float* __restrict__ sb1,
    const float* __restrict__ sb2, ushort_t* __restrict__ Out)
{
  const int m0 = blockIdx.x << 7;
  const int lvl = (m0 < 102400) ? 0 : (m0 < 128000 ? 1 : 2);
  const int CIN = (lvl==0)?128:(lvl==1?256:512);
  const int HW  = (lvl==0)?6400:(lvl==1?1600:400);
  const int noff= (lvl==0)?0:(lvl==1?102400:128000);
  const float* X = (lvl==0)?x0:(lvl==1?x1:x2);
  const ushort_t* Wl = Wb + ((lvl==0)?0:(lvl==1?12288:36864));
  const float* bias = (lvl==0)?sb0:(lvl==1?sb1:sb2);

  int t=threadIdx.x, lane=t&63, wv=t>>6, mr=lane&15, quad=lane>>4;

  int idx[2];
  #pragma unroll
  for (int nt=0; nt<2; ++nt) {
    int n = m0 + wv*32 + nt*16 + mr;
    int m = n - noff; int b_ = m / HW; int p = m - b_*HW;
    idx[nt] = (b_*CIN + quad*8)*HW + p;
  }
  const ushort_t* Ap = Wl + mr*CIN + quad*8;

  floatx4 zero = {0.f,0.f,0.f,0.f};
  floatx4 acc[6][2];
  #pragma unroll
  for (int i=0;i<6;++i)
    #pragma unroll
    for (int j=0;j<2;++j) acc[i][j] = zero;

  for (int k=0; k<CIN; k+=32) {
    short8 a[6], b[2];
    #pragma unroll
    for (int mt=0; mt<6; ++mt) a[mt] = *(const short8*)(Ap + mt*16*CIN);
    #pragma unroll
    for (int nt=0; nt<2; ++nt) {
      float f[8];
      #pragma unroll
      for (int j=0;j<8;++j) f[j] = X[idx[nt] + j*HW];
      int* bi = (int*)&b[nt];
      #pragma unroll
      for (int j=0;j<4;++j) bi[j] = (int)pack_rhu(f[2*j], f[2*j+1]);
    }
    #pragma unroll
    for (int mt=0; mt<6; ++mt)
      #pragma unroll
      for (int nt=0; nt<2; ++nt)
        acc[mt][nt] = __builtin_amdgcn_mfma_f32_16x16x32_bf16(a[mt], b[nt], acc[mt][nt], 0, 0, 0);
    Ap += 32;
    #pragma unroll
    for (int nt=0; nt<2; ++nt) idx[nt] += 32*HW;
  }

  #pragma unroll
  for (int mt=0; mt<6; ++mt) {
    float4 bv = *(const float4*)(bias + mt*16 + quad*4);
    #pragma unroll
    for (int nt=0; nt<2; ++nt) {
      int pos = m0 + wv*32 + nt*16 + mr;
      ushort4 o;
      o.x = f2bf(silu_f(acc[mt][nt][0] + bv.x));
      o.y = f2bf(silu_f(acc[mt][nt][1] + bv.y));
      o.z = f2bf(silu_f(acc[mt][nt][2] + bv.z));
      o.w = f2bf(silu_f(acc[mt][nt][3] + bv.w));
      *(ushort4*)(Out + (long)pos*96 + mt*16 + quad*4) = o;
    }
  }
}

// ---------------------------------------------------------------------------
// Expand GEMM: [n][96] bf16 -> [n][192] bf16 silu.
// Block = 128 pos (4 waves x 2 M-tiles), grid (1050, 2) (y = co half).
// ---------------------------------------------------------------------------
__global__ __launch_bounds__(256) void expand_k(
    const ushort_t* __restrict__ A, const ushort_t* __restrict__ Wb,
    const float* __restrict__ b1, ushort_t* __restrict__ Out)
{
  const int m0 = blockIdx.x << 7;
  const int lvl = (m0 < 102400) ? 0 : (m0 < 128000 ? 1 : 2);
  const int co0 = blockIdx.y * 96;
  int t = threadIdx.x, lane = t & 63, wv = t >> 6;
  int mr = lane & 15, quad = lane >> 4;
  const ushort_t* Ap = A + ((long)(m0 + wv*32 + mr))*96 + quad*8;
  const ushort_t* Bp = Wb + ((long)(co0 + mr))*96 + quad*8;
  const float* bp = b1 + lvl*192 + co0;

  floatx4 zero = {0.f,0.f,0.f,0.f};
  floatx4 acc[2][6];
  #pragma unroll
  for (int i=0;i<2;++i)
    #pragma unroll
    for (int j=0;j<6;++j) acc[i][j] = zero;

  #pragma unroll
  for (int k=0; k<3; ++k) {
    short8 a[2], b[6];
    #pragma unroll
    for (int mt=0; mt<2; ++mt) a[mt] = *(const short8*)(Ap + (long)mt*16*96);
    #pragma unroll
    for (int nt=0; nt<6; ++nt) b[nt] = *(const short8*)(Bp + (long)nt*16*96);
    #pragma unroll
    for (int mt=0; mt<2; ++mt)
      #pragma unroll
      for (int nt=0; nt<6; ++nt)
        acc[mt][nt] = __builtin_amdgcn_mfma_f32_16x16x32_bf16(a[mt], b[nt], acc[mt][nt], 0, 0, 0);
    Ap += 32; Bp += 32;
  }

  #pragma unroll
  for (int nt=0; nt<6; ++nt) {
    int co = co0 + nt*16 + mr;
    float bv = bp[nt*16 + mr];
    #pragma unroll
    for (int mt=0; mt<2; ++mt) {
      int gm = m0 + wv*32 + mt*16 + quad*4;
      #pragma unroll
      for (int r=0; r<4; ++r)
        Out[(long)(gm + r)*192 + co] = f2bf(silu_f(acc[mt][nt][r] + bv));
    }
  }
}

// ---------------------------------------------------------------------------
// Fused: dw3x3+SiLU (global reads, halo via L2) -> LDS -> project GEMM
// (K=192->96) + bias + residual -> LDS (reused) -> head.
// Block = 128 flat positions, 4 waves. grid 1050.
//   IS_CLS: 80-wide MFMA head + sigmoid -> out[...,5:85]
//   else:   per-thread 5-dot reg/obj + decode -> out[...,0:5]
// ---------------------------------------------------------------------------
template<bool IS_CLS>
__global__ __launch_bounds__(256) void dwproj_head_k(
    const ushort_t* __restrict__ ex, const ushort_t* __restrict__ wdT,
    const float* __restrict__ bd, const ushort_t* __restrict__ W2,
    const float* __restrict__ b2, const ushort_t* __restrict__ resid,
    const ushort_t* __restrict__ HWb, const float* __restrict__ hb,
    const float* __restrict__ rw, const float* __restrict__ rb,
    const float* __restrict__ ow, const float* __restrict__ ob,
    float* __restrict__ out)
{
  __shared__ ushort_t lds[128*196];          // dw out [p][c] stride 196
  ushort_t* ldsP = lds;                      // reused: proj out [p][co] stride 100
  const int m0 = blockIdx.x << 7;
  const int lvl = (m0 < 102400) ? 0 : (m0 < 128000 ? 1 : 2);
  const int HW  = (lvl==0) ? 6400 : (lvl==1 ? 1600 : 400);
  const int W   = (lvl==0) ? 80 : (lvl==1 ? 40 : 20);
  const int noff= (lvl==0) ? 0 : (lvl==1 ? 102400 : 128000);
  const int a0  = (lvl==0) ? 0 : (lvl==1 ? 6400 : 8000);

  int t = threadIdx.x, lane = t & 63, wv = t >> 6;
  int mr = lane & 15, quad = lane >> 4;

  // ---- phase 1: depthwise 3x3 + SiLU -> lds ----
  {
    const ushort_t* wT = wdT + lvl*1728;
    const float* bdl = bd + lvl*192;
    #pragma unroll
    for (int kk=0; kk<12; ++kk) {
      int idx = kk*256 + t;                  // 128*24 items
      int p_ = idx / 24; int g = idx - p_*24; int c = g*8;
      int n = m0 + p_;
      int m = n - noff;
      int b_ = m / HW; int rp = m - b_*HW;
      int y = rp / W;  int x = rp - y*W;
      float acc[8];
      *(float4*)(acc)   = *(const float4*)(bdl + c);
      *(float4*)(acc+4) = *(const float4*)(bdl + c + 4);
      const ushort_t* exn = ex + (long)n*192 + c;
      #pragma unroll
      for (int dy=-1; dy<=1; ++dy) {
        int yy = y + dy;
        if ((unsigned)yy < (unsigned)W) {
          #pragma unroll
          for (int dx=-1; dx<=1; ++dx) {
            int xx = x + dx;
            if ((unsigned)xx < (unsigned)W) {
              short8 a8 = *(const short8*)(exn + (long)(dy*W + dx)*192);
              short8 w8 = *(const short8*)(wT + ((dy+1)*3 + (dx+1))*192 + c);
              #pragma unroll
              for (int i=0;i<8;++i)
                acc[i] = fmaf(bf2f((ushort_t)a8[i]), bf2f((ushort_t)w8[i]), acc[i]);
            }
          }
        }
      }
      short8 o;
      #pragma unroll
      for (int i=0;i<8;++i) o[i] = (short)f2bf(silu_f(acc[i]));
      *(short8*)(lds + p_*196 + c) = o;
    }
  }
  __syncthreads();

  // ---- phase 2: project GEMM K=192 -> 96, + bias + residual ----
  floatx4 pacc[2][6];
  {
    const ushort_t* Bp = W2 + lvl*18432 + ((long)mr)*192 + quad*8;
    floatx4 zero = {0.f,0.f,0.f,0.f};
    #pragma unroll
    for (int i=0;i<2;++i)
      #pragma unroll
      for (int j=0;j<6;++j) pacc[i][j] = zero;

    #pragma unroll
    for (int k=0; k<6; ++k) {
      short8 a[2], b[6];
      #pragma unroll
      for (int mt=0; mt<2; ++mt)
        a[mt] = *(const short8*)(lds + (wv*32 + mt*16 + mr)*196 + k*32 + quad*8);
      #pragma unroll
      for (int nt=0; nt<6; ++nt)
        b[nt] = *(const short8*)(Bp + (long)nt*16*192 + k*32);
      #pragma unroll
      for (int mt=0; mt<2; ++mt)
        #pragma unroll
        for (int nt=0; nt<6; ++nt)
          pacc[mt][nt] = __builtin_amdgcn_mfma_f32_16x16x32_bf16(a[mt], b[nt], pacc[mt][nt], 0, 0, 0);
    }
  }
  __syncthreads();    // all dw-LDS reads done; safe to overwrite

  {
    const float* bp = b2 + lvl*96;
    #pragma unroll
    for (int nt=0; nt<6; ++nt) {
      int co = nt*16 + mr;
      float bv = bp[co];
      #pragma unroll
      for (int mt=0; mt<2; ++mt) {
        int row = wv*32 + mt*16 + quad*4;
        #pragma unroll
        for (int r=0; r<4; ++r) {
          float v = pacc[mt][nt][r] + bv + bf2f(resid[(long)(m0 + row + r)*96 + co]);
          ldsP[(row + r)*100 + co] = f2bf(v);
        }
      }
    }
  }
  __syncthreads();

  // ---- phase 3: head ----
  if (IS_CLS) {
    const ushort_t* Bp = HWb + lvl*7680 + ((long)mr)*96 + quad*8;
    const float* bp = hb + lvl*80;
    floatx4 zero = {0.f,0.f,0.f,0.f};
    floatx4 acc[2][5];
    #pragma unroll
    for (int i=0;i<2;++i)
      #pragma unroll
      for (int j=0;j<5;++j) acc[i][j] = zero;

    #pragma unroll
    for (int k=0; k<3; ++k) {
      short8 a[2], b[5];
      #pragma unroll
      for (int mt=0; mt<2; ++mt)
        a[mt] = *(const short8*)(ldsP + (wv*32 + mt*16 + mr)*100 + k*32 + quad*8);
      #pragma unroll
      for (int nt=0; nt<5; ++nt)
        b[nt] = *(const short8*)(Bp + (long)nt*16*96 + k*32);
      #pragma unroll
      for (int mt=0; mt<2; ++mt)
        #pragma unroll
        for (int nt=0; nt<5; ++nt)
          acc[mt][nt] = __builtin_amdgcn_mfma_f32_16x16x32_bf16(a[mt], b[nt], acc[mt][nt], 0, 0, 0);
    }

    #pragma unroll
    for (int nt=0; nt<5; ++nt) {
      int co = nt*16 + mr;
      float bv = bp[co];
      #pragma unroll
      for (int mt=0; mt<2; ++mt) {
        int pos = m0 + wv*32 + mt*16 + quad*4;
        #pragma unroll
        for (int r=0; r<4; ++r) {
          int m = pos + r - noff; int b_ = m / HW; int rp = m - b_*HW;
          out[((long)(b_*8400 + a0 + rp))*85 + 5 + co] = sigm_f(acc[mt][nt][r] + bv);
        }
      }
    }
  } else {
    if (t < 128) {
      int pos = m0 + t;
      float f[96];
      #pragma unroll
      for (int j=0;j<12;++j) {
        short8 v = *(const short8*)(ldsP + t*100 + j*8);
        #pragma unroll
        for (int i=0;i<8;++i) f[j*8+i] = bf2f((ushort_t)v[i]);
      }
      const float* w0 = rw + lvl*384;
      const float* wo = ow + lvl*96;
      float acc[5];
      #pragma unroll
      for (int c=0;c<4;++c) acc[c] = rb[lvl*4+c];
      acc[4] = ob[lvl];
      #pragma unroll 8
      for (int k=0;k<96;++k) {
        float fv = f[k];
        acc[0] = fmaf(fv, w0[k],      acc[0]);
        acc[1] = fmaf(fv, w0[96+k],   acc[1]);
        acc[2] = fmaf(fv, w0[192+k],  acc[2]);
        acc[3] = fmaf(fv, w0[288+k],  acc[3]);
        acc[4] = fmaf(fv, wo[k],      acc[4]);
      }
      float sc = (lvl==0) ? 8.f : (lvl==1 ? 16.f : 32.f);
      int m = pos - noff; int b_ = m / HW; int rp = m - b_*HW;
      int y = rp / W;  int x = rp - y*W;
      long o = ((long)(b_*8400 + a0 + rp))*85;
      out[o+0] = (acc[0] + (float)x)*sc;
      out[o+1] = (acc[1] + (float)y)*sc;
      out[o+2] = __expf(acc[2])*sc;
      out[o+3] = __expf(acc[3])*sc;
      out[o+4] = sigm_f(acc[4]);
    }
  }
}

extern "C" void kernel_launch(void* const* d_in, const int* in_sizes, int n_in,
                              void* d_out, int out_size, void* d_ws, size_t ws_size,
                              hipStream_t stream)
{
  bool dict = (in_sizes[1] == 96*128);
  const float* X[3]; const float* SW[3]; const float* SB[3];
  if (dict) {
    X[0]=(const float*)d_in[0]; SW[0]=(const float*)d_in[1]; SB[0]=(const float*)d_in[2];
    X[1]=(const float*)d_in[3]; SW[1]=(const float*)d_in[4]; SB[1]=(const float*)d_in[5];
    X[2]=(const float*)d_in[6]; SW[2]=(const float*)d_in[7]; SB[2]=(const float*)d_in[8];
  } else {
    X[0]=(const float*)d_in[0]; X[1]=(const float*)d_in[1]; X[2]=(const float*)d_in[2];
    SW[0]=(const float*)d_in[3]; SB[0]=(const float*)d_in[4];
    SW[1]=(const float*)d_in[5]; SB[1]=(const float*)d_in[6];
    SW[2]=(const float*)d_in[7]; SB[2]=(const float*)d_in[8];
  }
  const float* br_w1[2] = {(const float*)d_in[9],  (const float*)d_in[15]};
  const float* br_b1[2] = {(const float*)d_in[10], (const float*)d_in[16]};
  const float* br_wd[2] = {(const float*)d_in[11], (const float*)d_in[17]};
  const float* br_bd[2] = {(const float*)d_in[12], (const float*)d_in[18]};
  const float* br_w2[2] = {(const float*)d_in[13], (const float*)d_in[19]};
  const float* br_b2[2] = {(const float*)d_in[14], (const float*)d_in[20]};
  const float* clsp_w=(const float*)d_in[21]; const float* clsp_b=(const float*)d_in[22];
  const float* regp_w=(const float*)d_in[23]; const float* regp_b=(const float*)d_in[24];
  const float* objp_w=(const float*)d_in[25]; const float* objp_b=(const float*)d_in[26];

  float* out = (float*)d_out;

  // workspace layout (ushort units)
  ushort_t* wbf   = (ushort_t*)d_ws;            // 340,608
  ushort_t* stemO = wbf + 340608;               // 134400*96 = 12,902,400
  ushort_t* bufA  = stemO + 12902400;           // 134400*192 = 25,804,800 (expand out)

  // 1. weights -> bf16 blob
  wconv_k<<<1331,256,0,stream>>>(SW[0],SW[1],SW[2],br_w1[0],br_w1[1],
                                 br_w2[0],br_w2[1],clsp_w,br_wd[0],br_wd[1],wbf);

  // 2. stem GEMM straight from NCHW fp32
  stem_k<<<1050,256,0,stream>>>(X[0],X[1],X[2],wbf,SB[0],SB[1],SB[2],stemO);

  for (int br=0; br<2; ++br) {   // 0 = cls, 1 = reg
    // 3. expand GEMM: stemO -> bufA [n][192], silu
    expand_k<<<dim3(1050,2),256,0,stream>>>(
        stemO, wbf + (br ? 141312 : 86016), br_b1[br], bufA);
    // 4. dw + project + residual + head, fused
    if (br == 0)
      dwproj_head_k<true><<<1050,256,0,stream>>>(
          bufA, wbf + 330240, br_bd[0], wbf + 196608, br_b2[0], stemO,
          wbf + 307200, clsp_b, nullptr, nullptr, nullptr, nullptr, out);
    else
      dwproj_head_k<false><<<1050,256,0,stream>>>(
          bufA, wbf + 335424, br_bd[1], wbf + 251904, br_b2[1], stemO,
          nullptr, nullptr, regp_w, regp_b, objp_w, objp_b, out);
  }
}

// Round 6
// 484.567 us; speedup vs baseline: 1.1698x; 1.1698x over previous
//
#include <hip/hip_runtime.h>

#define NB 16

typedef unsigned short ushort_t;
typedef unsigned int uint32;
using short8  = __attribute__((ext_vector_type(8))) short;
using floatx4 = __attribute__((ext_vector_type(4))) float;

__device__ __forceinline__ float silu_f(float x){ return x * (1.0f/(1.0f+__expf(-x))); }
__device__ __forceinline__ float sigm_f(float x){ return 1.0f/(1.0f+__expf(-x)); }
__device__ __forceinline__ ushort_t f2bf(float f){
  uint32 u = __float_as_uint(f);
  u += 0x7fffu + ((u>>16)&1u);          // RNE
  return (ushort_t)(u>>16);
}
__device__ __forceinline__ float bf2f(ushort_t h){ return __uint_as_float(((uint32)h)<<16); }
// round-half-up bf16 pair pack: 3 VALU ops per 2 elements
__device__ __forceinline__ uint32 pack_rhu(float f0, float f1){
  uint32 u0 = __float_as_uint(f0) + 0x8000u;
  uint32 u1 = __float_as_uint(f1) + 0x8000u;
  return __builtin_amdgcn_perm(u1, u0, 0x07060302u);  // {u1.hi16, u0.hi16}
}

// ---------------------------------------------------------------------------
// Weight conversion to one bf16 blob. ushort offsets:
//   0        stemW0 12288
//   12288    stemW1 24576
//   36864    stemW2 49152
//   86016    cls_w1 55296     (86016 + bz*55296)
//   141312   reg_w1 55296
//   196608   cls_w2 55296     (196608 + bz*55296)
//   251904   reg_w2 55296
//   307200   clsp_w 23040
//   330240   cls_wdT 5184     (330240 + bz*5184) [lvl][j][c]
//   335424   reg_wdT 5184
//   340608   total
// ---------------------------------------------------------------------------
__global__ __launch_bounds__(256) void wconv_k(
    const float* __restrict__ s0, const float* __restrict__ s1,
    const float* __restrict__ s2, const float* __restrict__ cw1,
    const float* __restrict__ rw1, const float* __restrict__ cw2,
    const float* __restrict__ rw2, const float* __restrict__ chw,
    const float* __restrict__ cwd, const float* __restrict__ rwd,
    ushort_t* __restrict__ dst)
{
  int i = blockIdx.x*256 + threadIdx.x;
  if (i >= 340608) return;
  if (i < 330240) {
    const float* p; int off;
    if      (i < 12288)  { p = s0;  off = i; }
    else if (i < 36864)  { p = s1;  off = i - 12288; }
    else if (i < 86016)  { p = s2;  off = i - 36864; }
    else if (i < 141312) { p = cw1; off = i - 86016; }
    else if (i < 196608) { p = rw1; off = i - 141312; }
    else if (i < 251904) { p = cw2; off = i - 196608; }
    else if (i < 307200) { p = rw2; off = i - 251904; }
    else                 { p = chw; off = i - 307200; }
    dst[i] = f2bf(p[off]);
  } else {
    int rel = i - 330240;
    int br = rel / 5184; int r2 = rel - br*5184;
    int lvl = r2 / 1728; int r3 = r2 - lvl*1728;
    int j = r3 / 192;    int c = r3 - j*192;
    const float* wd = br ? rwd : cwd;
    dst[i] = f2bf(wd[lvl*1728 + c*9 + j]);
  }
}

// ---------------------------------------------------------------------------
// Stem GEMM directly from NCHW fp32. A = weights [co][ci] (6 M-tiles of 16),
// B = x NCHW (positions). Block = 128 pos (4 waves x 32 pos), grid 1050.
// ---------------------------------------------------------------------------
__global__ __launch_bounds__(256) void stem_k(
    const float* __restrict__ x0, const float* __restrict__ x1,
    const float* __restrict__ x2, const ushort_t* __restrict__ Wb,
    const float* __restrict__ sb0, const float* __restrict__ sb1,
    const float* __restrict__ sb2, ushort_t* __restrict__ Out)
{
  const int m0 = blockIdx.x << 7;
  const int lvl = (m0 < 102400) ? 0 : (m0 < 128000 ? 1 : 2);
  const int CIN = (lvl==0)?128:(lvl==1?256:512);
  const int HW  = (lvl==0)?6400:(lvl==1?1600:400);
  const int noff= (lvl==0)?0:(lvl==1?102400:128000);
  const float* X = (lvl==0)?x0:(lvl==1?x1:x2);
  const ushort_t* Wl = Wb + ((lvl==0)?0:(lvl==1?12288:36864));
  const float* bias = (lvl==0)?sb0:(lvl==1?sb1:sb2);

  int t=threadIdx.x, lane=t&63, wv=t>>6, mr=lane&15, quad=lane>>4;

  int idx[2];
  #pragma unroll
  for (int nt=0; nt<2; ++nt) {
    int n = m0 + wv*32 + nt*16 + mr;
    int m = n - noff; int b_ = m / HW; int p = m - b_*HW;
    idx[nt] = (b_*CIN + quad*8)*HW + p;
  }
  const ushort_t* Ap = Wl + mr*CIN + quad*8;

  floatx4 zero = {0.f,0.f,0.f,0.f};
  floatx4 acc[6][2];
  #pragma unroll
  for (int i=0;i<6;++i)
    #pragma unroll
    for (int j=0;j<2;++j) acc[i][j] = zero;

  for (int k=0; k<CIN; k+=32) {
    short8 a[6], b[2];
    #pragma unroll
    for (int mt=0; mt<6; ++mt) a[mt] = *(const short8*)(Ap + mt*16*CIN);
    #pragma unroll
    for (int nt=0; nt<2; ++nt) {
      float f[8];
      #pragma unroll
      for (int j=0;j<8;++j) f[j] = X[idx[nt] + j*HW];
      int* bi = (int*)&b[nt];
      #pragma unroll
      for (int j=0;j<4;++j) bi[j] = (int)pack_rhu(f[2*j], f[2*j+1]);
    }
    #pragma unroll
    for (int mt=0; mt<6; ++mt)
      #pragma unroll
      for (int nt=0; nt<2; ++nt)
        acc[mt][nt] = __builtin_amdgcn_mfma_f32_16x16x32_bf16(a[mt], b[nt], acc[mt][nt], 0, 0, 0);
    Ap += 32;
    #pragma unroll
    for (int nt=0; nt<2; ++nt) idx[nt] += 32*HW;
  }

  #pragma unroll
  for (int mt=0; mt<6; ++mt) {
    float4 bv = *(const float4*)(bias + mt*16 + quad*4);
    #pragma unroll
    for (int nt=0; nt<2; ++nt) {
      int pos = m0 + wv*32 + nt*16 + mr;
      ushort4 o;
      o.x = f2bf(silu_f(acc[mt][nt][0] + bv.x));
      o.y = f2bf(silu_f(acc[mt][nt][1] + bv.y));
      o.z = f2bf(silu_f(acc[mt][nt][2] + bv.z));
      o.w = f2bf(silu_f(acc[mt][nt][3] + bv.w));
      *(ushort4*)(Out + (long)pos*96 + mt*16 + quad*4) = o;
    }
  }
}

// ---------------------------------------------------------------------------
// Expand GEMM, BOTH branches: [n][96] -> [n][192] silu bf16.
// grid (1050, 2, 2): x = 128-pos tile, y = co half, z = branch.
// ---------------------------------------------------------------------------
__global__ __launch_bounds__(256) void expand2_k(
    const ushort_t* __restrict__ A, const ushort_t* __restrict__ wbf,
    const float* __restrict__ b1c, const float* __restrict__ b1r,
    ushort_t* __restrict__ OutBase)
{
  const int bz = blockIdx.z;
  const ushort_t* Wb = wbf + 86016 + bz*55296;
  ushort_t* Out = OutBase + (long)bz*25804800;
  const float* b1 = bz ? b1r : b1c;

  const int m0 = blockIdx.x << 7;
  const int lvl = (m0 < 102400) ? 0 : (m0 < 128000 ? 1 : 2);
  const int co0 = blockIdx.y * 96;
  int t = threadIdx.x, lane = t & 63, wv = t >> 6;
  int mr = lane & 15, quad = lane >> 4;
  const ushort_t* Ap = A + ((long)(m0 + wv*32 + mr))*96 + quad*8;
  const ushort_t* Bp = Wb + ((long)(co0 + mr))*96 + quad*8;
  const float* bp = b1 + lvl*192 + co0;

  floatx4 zero = {0.f,0.f,0.f,0.f};
  floatx4 acc[2][6];
  #pragma unroll
  for (int i=0;i<2;++i)
    #pragma unroll
    for (int j=0;j<6;++j) acc[i][j] = zero;

  #pragma unroll
  for (int k=0; k<3; ++k) {
    short8 a[2], b[6];
    #pragma unroll
    for (int mt=0; mt<2; ++mt) a[mt] = *(const short8*)(Ap + (long)mt*16*96);
    #pragma unroll
    for (int nt=0; nt<6; ++nt) b[nt] = *(const short8*)(Bp + (long)nt*16*96);
    #pragma unroll
    for (int mt=0; mt<2; ++mt)
      #pragma unroll
      for (int nt=0; nt<6; ++nt)
        acc[mt][nt] = __builtin_amdgcn_mfma_f32_16x16x32_bf16(a[mt], b[nt], acc[mt][nt], 0, 0, 0);
    Ap += 32; Bp += 32;
  }

  #pragma unroll
  for (int nt=0; nt<6; ++nt) {
    int co = co0 + nt*16 + mr;
    float bv = bp[nt*16 + mr];
    #pragma unroll
    for (int mt=0; mt<2; ++mt) {
      int gm = m0 + wv*32 + mt*16 + quad*4;
      #pragma unroll
      for (int r=0; r<4; ++r)
        Out[(long)(gm + r)*192 + co] = f2bf(silu_f(acc[mt][nt][r] + bv));
    }
  }
}

// ---------------------------------------------------------------------------
// Fused dw3x3+SiLU -> LDS -> project GEMM + bias + residual -> LDS -> head,
// BOTH branches. grid (2100, 2): x = 64-pos tile, y = branch.
// Block = 256 thr = 4 waves; wave owns one 16-row M-tile.
// LDS 25 KB -> ~6 blocks/CU.
// ---------------------------------------------------------------------------
__global__ __launch_bounds__(256) void dwproj2_k(
    const ushort_t* __restrict__ exBase, const ushort_t* __restrict__ wbf,
    const float* __restrict__ bd_c, const float* __restrict__ bd_r,
    const float* __restrict__ b2_c, const float* __restrict__ b2_r,
    const ushort_t* __restrict__ resid,
    const float* __restrict__ hb, const float* __restrict__ rw,
    const float* __restrict__ rb, const float* __restrict__ ow,
    const float* __restrict__ ob, float* __restrict__ out)
{
  __shared__ ushort_t lds[64*196];           // dw out [p][c] stride 196 (25 KB)
  ushort_t* ldsP = lds;                      // reused: proj out [p][co] stride 100
  const int bz = blockIdx.y;
  const ushort_t* ex = exBase + (long)bz*25804800;
  const float* bd = bz ? bd_r : bd_c;
  const float* b2 = bz ? b2_r : b2_c;

  const int m0 = blockIdx.x << 6;
  const int lvl = (m0 < 102400) ? 0 : (m0 < 128000 ? 1 : 2);
  const int HW  = (lvl==0) ? 6400 : (lvl==1 ? 1600 : 400);
  const int W   = (lvl==0) ? 80 : (lvl==1 ? 40 : 20);
  const int noff= (lvl==0) ? 0 : (lvl==1 ? 102400 : 128000);
  const int a0  = (lvl==0) ? 0 : (lvl==1 ? 6400 : 8000);

  int t = threadIdx.x, lane = t & 63, wv = t >> 6;
  int mr = lane & 15, quad = lane >> 4;

  // ---- phase 1: depthwise 3x3 + SiLU -> lds ----
  {
    const ushort_t* wT = wbf + 330240 + bz*5184 + lvl*1728;
    const float* bdl = bd + lvl*192;
    #pragma unroll
    for (int kk=0; kk<6; ++kk) {
      int idx = kk*256 + t;                  // 64*24 items
      int p_ = idx / 24; int g = idx - p_*24; int c = g*8;
      int n = m0 + p_;
      int m = n - noff;
      int b_ = m / HW; int rp = m - b_*HW;
      int y = rp / W;  int x = rp - y*W;
      float acc[8];
      *(float4*)(acc)   = *(const float4*)(bdl + c);
      *(float4*)(acc+4) = *(const float4*)(bdl + c + 4);
      const ushort_t* exn = ex + (long)n*192 + c;
      #pragma unroll
      for (int dy=-1; dy<=1; ++dy) {
        int yy = y + dy;
        if ((unsigned)yy < (unsigned)W) {
          #pragma unroll
          for (int dx=-1; dx<=1; ++dx) {
            int xx = x + dx;
            if ((unsigned)xx < (unsigned)W) {
              short8 a8 = *(const short8*)(exn + (long)(dy*W + dx)*192);
              short8 w8 = *(const short8*)(wT + ((dy+1)*3 + (dx+1))*192 + c);
              #pragma unroll
              for (int i=0;i<8;++i)
                acc[i] = fmaf(bf2f((ushort_t)a8[i]), bf2f((ushort_t)w8[i]), acc[i]);
            }
          }
        }
      }
      short8 o;
      #pragma unroll
      for (int i=0;i<8;++i) o[i] = (short)f2bf(silu_f(acc[i]));
      *(short8*)(lds + p_*196 + c) = o;
    }
  }
  __syncthreads();

  // ---- phase 2: project GEMM K=192 -> 96, + bias + residual ----
  floatx4 pacc[6];
  {
    const ushort_t* Bp = wbf + 196608 + bz*55296 + lvl*18432 + ((long)mr)*192 + quad*8;
    floatx4 zero = {0.f,0.f,0.f,0.f};
    #pragma unroll
    for (int j=0;j<6;++j) pacc[j] = zero;

    #pragma unroll
    for (int k=0; k<6; ++k) {
      short8 a = *(const short8*)(lds + (wv*16 + mr)*196 + k*32 + quad*8);
      short8 b[6];
      #pragma unroll
      for (int nt=0; nt<6; ++nt)
        b[nt] = *(const short8*)(Bp + (long)nt*16*192 + k*32);
      #pragma unroll
      for (int nt=0; nt<6; ++nt)
        pacc[nt] = __builtin_amdgcn_mfma_f32_16x16x32_bf16(a, b[nt], pacc[nt], 0, 0, 0);
    }
  }
  __syncthreads();    // all dw-LDS reads done; safe to overwrite

  {
    const float* bp = b2 + lvl*96;
    #pragma unroll
    for (int nt=0; nt<6; ++nt) {
      int co = nt*16 + mr;
      float bv = bp[co];
      int row = wv*16 + quad*4;
      #pragma unroll
      for (int r=0; r<4; ++r) {
        float v = pacc[nt][r] + bv + bf2f(resid[(long)(m0 + row + r)*96 + co]);
        ldsP[(row + r)*100 + co] = f2bf(v);
      }
    }
  }
  // NOTE: head below reads only rows written by this same wave -> no barrier.

  // ---- phase 3: head ----
  if (bz == 0) {
    const ushort_t* Bp = wbf + 307200 + lvl*7680 + ((long)mr)*96 + quad*8;
    const float* bp = hb + lvl*80;
    floatx4 zero = {0.f,0.f,0.f,0.f};
    floatx4 acc[5];
    #pragma unroll
    for (int j=0;j<5;++j) acc[j] = zero;

    #pragma unroll
    for (int k=0; k<3; ++k) {
      short8 a = *(const short8*)(ldsP + (wv*16 + mr)*100 + k*32 + quad*8);
      short8 b[5];
      #pragma unroll
      for (int nt=0; nt<5; ++nt)
        b[nt] = *(const short8*)(Bp + (long)nt*16*96 + k*32);
      #pragma unroll
      for (int nt=0; nt<5; ++nt)
        acc[nt] = __builtin_amdgcn_mfma_f32_16x16x32_bf16(a, b[nt], acc[nt], 0, 0, 0);
    }

    #pragma unroll
    for (int nt=0; nt<5; ++nt) {
      int co = nt*16 + mr;
      float bv = bp[co];
      int pos = m0 + wv*16 + quad*4;
      #pragma unroll
      for (int r=0; r<4; ++r) {
        int m = pos + r - noff; int b_ = m / HW; int rp = m - b_*HW;
        out[((long)(b_*8400 + a0 + rp))*85 + 5 + co] = sigm_f(acc[nt][r] + bv);
      }
    }
  } else {
    if (t < 64) {
      int pos = m0 + t;
      const float* w0 = rw + lvl*384;
      const float* wo = ow + lvl*96;
      float acc[5];
      #pragma unroll
      for (int c=0;c<4;++c) acc[c] = rb[lvl*4+c];
      acc[4] = ob[lvl];
      #pragma unroll
      for (int j=0;j<12;++j) {
        short8 v = *(const short8*)(ldsP + t*100 + j*8);
        #pragma unroll
        for (int i=0;i<8;++i) {
          float fv = bf2f((ushort_t)v[i]);
          int k = j*8+i;
          acc[0] = fmaf(fv, w0[k],      acc[0]);
          acc[1] = fmaf(fv, w0[96+k],   acc[1]);
          acc[2] = fmaf(fv, w0[192+k],  acc[2]);
          acc[3] = fmaf(fv, w0[288+k],  acc[3]);
          acc[4] = fmaf(fv, wo[k],      acc[4]);
        }
      }
      float sc = (lvl==0) ? 8.f : (lvl==1 ? 16.f : 32.f);
      int m = pos - noff; int b_ = m / HW; int rp = m - b_*HW;
      int y = rp / W;  int x = rp - y*W;
      long o = ((long)(b_*8400 + a0 + rp))*85;
      out[o+0] = (acc[0] + (float)x)*sc;
      out[o+1] = (acc[1] + (float)y)*sc;
      out[o+2] = __expf(acc[2])*sc;
      out[o+3] = __expf(acc[3])*sc;
      out[o+4] = sigm_f(acc[4]);
    }
  }
}

extern "C" void kernel_launch(void* const* d_in, const int* in_sizes, int n_in,
                              void* d_out, int out_size, void* d_ws, size_t ws_size,
                              hipStream_t stream)
{
  bool dict = (in_sizes[1] == 96*128);
  const float* X[3]; const float* SW[3]; const float* SB[3];
  if (dict) {
    X[0]=(const float*)d_in[0]; SW[0]=(const float*)d_in[1]; SB[0]=(const float*)d_in[2];
    X[1]=(const float*)d_in[3]; SW[1]=(const float*)d_in[4]; SB[1]=(const float*)d_in[5];
    X[2]=(const float*)d_in[6]; SW[2]=(const float*)d_in[7]; SB[2]=(const float*)d_in[8];
  } else {
    X[0]=(const float*)d_in[0]; X[1]=(const float*)d_in[1]; X[2]=(const float*)d_in[2];
    SW[0]=(const float*)d_in[3]; SB[0]=(const float*)d_in[4];
    SW[1]=(const float*)d_in[5]; SB[1]=(const float*)d_in[6];
    SW[2]=(const float*)d_in[7]; SB[2]=(const float*)d_in[8];
  }
  const float* br_w1[2] = {(const float*)d_in[9],  (const float*)d_in[15]};
  const float* br_b1[2] = {(const float*)d_in[10], (const float*)d_in[16]};
  const float* br_wd[2] = {(const float*)d_in[11], (const float*)d_in[17]};
  const float* br_bd[2] = {(const float*)d_in[12], (const float*)d_in[18]};
  const float* br_w2[2] = {(const float*)d_in[13], (const float*)d_in[19]};
  const float* br_b2[2] = {(const float*)d_in[14], (const float*)d_in[20]};
  const float* clsp_w=(const float*)d_in[21]; const float* clsp_b=(const float*)d_in[22];
  const float* regp_w=(const float*)d_in[23]; const float* regp_b=(const float*)d_in[24];
  const float* objp_w=(const float*)d_in[25]; const float* objp_b=(const float*)d_in[26];

  float* out = (float*)d_out;

  // workspace layout (ushort units): 340608 + 12.9M + 2*25.8M = 129.7 MB
  ushort_t* wbf   = (ushort_t*)d_ws;            // 340,608
  ushort_t* stemO = wbf + 340608;               // 134400*96 = 12,902,400
  ushort_t* bufA  = stemO + 12902400;           // 2 x 25,804,800 (expand, per branch)

  // 1. weights -> bf16 blob
  wconv_k<<<1331,256,0,stream>>>(SW[0],SW[1],SW[2],br_w1[0],br_w1[1],
                                 br_w2[0],br_w2[1],clsp_w,br_wd[0],br_wd[1],wbf);

  // 2. stem GEMM straight from NCHW fp32
  stem_k<<<1050,256,0,stream>>>(X[0],X[1],X[2],wbf,SB[0],SB[1],SB[2],stemO);

  // 3. expand GEMM, both branches in one dispatch
  expand2_k<<<dim3(1050,2,2),256,0,stream>>>(stemO, wbf, br_b1[0], br_b1[1], bufA);

  // 4. dw + project + residual + head, both branches in one dispatch
  dwproj2_k<<<dim3(2100,2),256,0,stream>>>(
      bufA, wbf, br_bd[0], br_bd[1], br_b2[0], br_b2[1], stemO,
      clsp_b, regp_w, regp_b, objp_w, objp_b, out);
}